// Round 13
// baseline (178.651 us; speedup 1.0000x reference)
//
#include <hip/hip_runtime.h>
#include <hip/hip_bf16.h>
#include <stdint.h>

// Attention: b=4, n=4097, d=128, h=8, dh=16, scale = d**-0.5.
// Interface (R5): fp32 in, fp32 out, ws >= 33.6MB usable.
// R26: R25's dense-merge gained only ~2us -> out's read pattern was never
// the residual; theory now: qkv/out run at 16 waves/CU (1025 blocks x 4
// waves = grid-capped residency) in a load-latency regime (~1.4 TB/s
// effective). Fix = double resident waves at CONSTANT work (R14's failure
// was redundant work, not wave count):
//   qkv: 512-thread blocks, 8 waves x 3 single n-tiles (ntc = w, w+8, w+16);
//        un-paired accumulator lowers VGPR for 8-wave/SIMD residency.
//   out: 512-thread blocks, 2 m-tiles/block (513 blocks); merge uses all
//        512 threads over 32 tokens; phase2 = 8 waves = (tile, nt-pair);
//        Wout loads moved into the kk-loop (TLP hides them, lower VGPR).
// attn/prep byte-frozen from R25 (PACC [ROWS][NSP][DD], PL [ROWS][HH][NSP]).

#define BB 4
#define NN 4097
#define NNP 4112
#define DD 128
#define HH 8
#define DH 16
#define BH (BB*HH)    // 32
#define ROWS (BB*NN)  // 16388
#define MT  1025      // ceil(ROWS/16) m-tiles
#define NSP 4         // attention key-splits (R13-proven)

typedef _Float16 h4 __attribute__((ext_vector_type(4)));
typedef _Float16 h8 __attribute__((ext_vector_type(8)));
typedef __fp16   fp16v2 __attribute__((ext_vector_type(2)));
typedef float    f4 __attribute__((ext_vector_type(4)));

#define QSCALE (0.08838834764831845f * 1.4426950408889634f)  // 128^-.5 * log2e

#if __has_builtin(__builtin_amdgcn_exp2f)
#define EXP2F(x) __builtin_amdgcn_exp2f(x)
#else
#define EXP2F(x) exp2f(x)
#endif

union H4u { h4 v; fp16v2 p[2]; };
union H8u { h8 v; fp16v2 p[4]; };

static __device__ __forceinline__ H4u pack4u(float a, float b, float c, float d) {
    H4u u;
#if __has_builtin(__builtin_amdgcn_cvt_pkrtz)
    u.p[0] = __builtin_amdgcn_cvt_pkrtz(a, b);
    u.p[1] = __builtin_amdgcn_cvt_pkrtz(c, d);
#else
    u.v[0] = (_Float16)a; u.v[1] = (_Float16)b; u.v[2] = (_Float16)c; u.v[3] = (_Float16)d;
#endif
    return u;
}

static __device__ __forceinline__ h8 pack8u(const float4& t0, const float4& t1) {
    H8u u;
#if __has_builtin(__builtin_amdgcn_cvt_pkrtz)
    u.p[0] = __builtin_amdgcn_cvt_pkrtz(t0.x, t0.y);
    u.p[1] = __builtin_amdgcn_cvt_pkrtz(t0.z, t0.w);
    u.p[2] = __builtin_amdgcn_cvt_pkrtz(t1.x, t1.y);
    u.p[3] = __builtin_amdgcn_cvt_pkrtz(t1.z, t1.w);
#else
    u.v[0]=(_Float16)t0.x; u.v[1]=(_Float16)t0.y; u.v[2]=(_Float16)t0.z; u.v[3]=(_Float16)t0.w;
    u.v[4]=(_Float16)t1.x; u.v[5]=(_Float16)t1.y; u.v[6]=(_Float16)t1.z; u.v[7]=(_Float16)t1.w;
#endif
    return u.v;
}

// ---------------- K0: prep — W_qkv^T (Q-scaled) + W_out^T in f16 -------
__global__ __launch_bounds__(256) void prep(
    const float* __restrict__ Wqkv,
    const float* __restrict__ Wout,
    _Float16* __restrict__ WqkvT,   // [384][128], rows 0..127 pre-scaled by QSCALE
    _Float16* __restrict__ WoutT)   // [128][128]
{
    const int id = blockIdx.x*256 + threadIdx.x;
    if (id < 384*128) {
        const int n = id >> 7, k = id & 127;
        const float s = (n < 128) ? QSCALE : 1.0f;
        WqkvT[id] = (_Float16)(Wqkv[k*384 + n] * s);
    } else if (id < 384*128 + 128*128) {
        const int e = id - 384*128;
        const int n = e >> 7, k = e & 127;
        WoutT[e] = (_Float16)(Wout[k*128 + n]);
    }
}

// ---------------- K1: qkv = x @ WqkvT^T + b, via K=32 MFMA (R26: 8 waves) -----
// D[m=quad*4+reg][n=l16]; A[m=l16][k=quad*8+j]; B[k=quad*8+j][n=l16].
// 512-thread blocks: wave w handles ntc = {w, w+8, w+16} (Q/K/V head w).
__global__ __launch_bounds__(512) void qkv_mfma(
    const float* __restrict__ x,
    const _Float16* __restrict__ WqkvT,
    const float* __restrict__ bqkv,
    _Float16* __restrict__ Qh,    // [BH][NNP][16]
    _Float16* __restrict__ Kh,    // [BH][NNP][16]
    _Float16* __restrict__ Vt)    // [BH][16][NNP] (transposed, attn-ready)
{
    __shared__ _Float16 tile[16][264];            // [local token][ntc*16+dim] Q/K only
    const int wid  = blockIdx.x;                  // m-tile 0..1024
    const int wave = threadIdx.x >> 6;            // 0..7
    const int lane = threadIdx.x & 63;
    const int quad = lane >> 4, l16 = lane & 15;

    const int rowlo = wid*16;
    const int blo   = rowlo / NN;
    const bool vfast = (rowlo + 15 < ROWS) && (rowlo + 15 - blo*NN < NN);
    const int nrow0 = rowlo - blo*NN;

    const int arow = rowlo + l16;
    const int arc  = (arow < ROWS) ? arow : (ROWS - 1);
    const float* xr = x + (size_t)arc*DD;
    h8 af[4];
    #pragma unroll
    for (int kk = 0; kk < 4; ++kk) {
        const float4 t0 = *(const float4*)(xr + kk*32 + quad*8);
        const float4 t1 = *(const float4*)(xr + kk*32 + quad*8 + 4);
        af[kk] = pack8u(t0, t1);
    }

    #pragma unroll
    for (int i = 0; i < 3; ++i) {
        const int ntc = wave + 8*i;                // 0..23; wave w: Q/K/V of head w
        const float b0 = bqkv[ntc*16 + l16] * ((ntc < 8) ? QSCALE : 1.0f);
        f4 a0 = {b0,b0,b0,b0};
        #pragma unroll
        for (int kk = 0; kk < 4; ++kk) {
            const h8 bf0 = *(const h8*)(WqkvT + (size_t)(ntc*16 + l16)*DD + kk*32 + quad*8);
            a0 = __builtin_amdgcn_mfma_f32_16x16x32_f16(af[kk], bf0, a0, 0, 0, 0);
        }
        if (ntc < 16) {        // Q/K -> LDS stage
            #pragma unroll
            for (int r = 0; r < 4; ++r)
                tile[quad*4 + r][ntc*16 + l16] = (_Float16)a0[r];
        } else {               // V -> direct transposed store
            const int head = ntc & 7;
            if (vfast) {
                h4 pk;
                pk[0] = (_Float16)a0[0]; pk[1] = (_Float16)a0[1];
                pk[2] = (_Float16)a0[2]; pk[3] = (_Float16)a0[3];
                *(h4*)(Vt + ((size_t)(blo*HH + head)*DH + l16)*NNP + nrow0 + quad*4) = pk;
            } else {
                #pragma unroll
                for (int r = 0; r < 4; ++r) {
                    const int row = rowlo + quad*4 + r;
                    if (row < ROWS) {
                        const int bidx = row / NN;
                        const int nrow = row - bidx*NN;
                        Vt[((size_t)(bidx*HH + head)*DH + l16)*NNP + nrow] = (_Float16)a0[r];
                    }
                }
            }
        }
    }
    __syncthreads();

    // write phase (Q/K): unit = (ntc, local token); 16-dim head-row = 2x h8 (32B)
    if (threadIdx.x < 384) {
        const int u   = threadIdx.x;   // 16 ntc x 16 tokens... wait: 24? No: 16 Q/K ntc
        const int ntc = u >> 4, lt = u & 15;     // ntc 0..23 covers 384/16=24 -> only 0..15 used below
        const int row = rowlo + lt;
        if (ntc < 16 && row < ROWS) {
            _Float16* base = (ntc < 8) ? Qh : Kh;
            const int head = ntc & 7;
            const int bidx = row / NN;
            const int nrow = row - bidx*NN;
            _Float16* dst = base + ((size_t)(bidx*HH + head)*NNP + nrow)*DH;
            *(h8*)dst       = *(const h8*)&tile[lt][ntc*16];
            *(h8*)(dst + 8) = *(const h8*)&tile[lt][ntc*16 + 8];
        }
    }
}

// ---------------- K2: MFMA flash attention (R13/R18 body; R25 PACC layout) ----
__global__ __launch_bounds__(256, 8) void attn_mfma(
    const _Float16* __restrict__ Qh,
    const _Float16* __restrict__ Kh,
    const _Float16* __restrict__ Vt,
    _Float16* __restrict__ PACC,   // [ROWS][NSP][DD] per-split normalized out (f16)
    float* __restrict__ PL)        // [ROWS][HH][NSP] per-split row sums
{
    const int qt   = blockIdx.x;       // 0..16
    const int bh   = blockIdx.y;       // 0..31
    const int sp   = blockIdx.z;       // 0..3
    const int tid  = threadIdx.x;
    const int wave = tid >> 6;
    const int lane = tid & 63;
    const int quad = lane >> 4;
    const int l16  = lane & 15;
    const int bidx = bh >> 3, head = bh & 7;

    const int qbase = qt*256 + wave*64;

    const _Float16* Qb = Qh + (size_t)bh*NNP*DH;
    h4 qf[4];
    #pragma unroll
    for (int g = 0; g < 4; ++g) {
        const int qr = qbase + g*16 + l16;
        const int qc = (qr < NN) ? qr : (NN-1);
        qf[g] = *(const h4*)(Qb + (size_t)qc*DH + quad*4);
    }

    f4 acc[4] = {{0,0,0,0},{0,0,0,0},{0,0,0,0},{0,0,0,0}};
    float ls[4] = {0.f,0.f,0.f,0.f};

    const int t0 = sp*64;
    const int t1 = t0 + 64;

    const _Float16* kp = Kh + ((size_t)bh*NNP + (size_t)t0*16 + l16)*DH + quad*4;
    const _Float16* vp = Vt + ((size_t)bh*DH + l16)*NNP + t0*16 + quad*4;

    h4 ak = *(const h4*)kp;
    h4 av = *(const h4*)vp;
    const f4 zero = {0.f,0.f,0.f,0.f};
#if __has_builtin(__builtin_amdgcn_fdot2)
    const fp16v2 one2 = {(__fp16)1.0f, (__fp16)1.0f};
#endif

    for (int tt = t0; tt < t1; ++tt) {
        kp += 16*DH; vp += 16;
        const h4 nak = *(const h4*)kp;   // prefetch (tile <= 256 in-bounds)
        const h4 nav = *(const h4*)vp;
        #pragma unroll
        for (int g = 0; g < 4; ++g) {
            f4 d = __builtin_amdgcn_mfma_f32_16x16x16f16(ak, qf[g], zero, 0, 0, 0);
            const float p0 = EXP2F(d[0]), p1 = EXP2F(d[1]), p2 = EXP2F(d[2]), p3 = EXP2F(d[3]);
            const H4u pb = pack4u(p0, p1, p2, p3);
#if __has_builtin(__builtin_amdgcn_fdot2)
            ls[g] = __builtin_amdgcn_fdot2(pb.p[0], one2,
                     __builtin_amdgcn_fdot2(pb.p[1], one2, ls[g], false), false);
#else
            ls[g] += (p0 + p1) + (p2 + p3);
#endif
            acc[g] = __builtin_amdgcn_mfma_f32_16x16x16f16(av, pb.v, acc[g], 0, 0, 0);
        }
        ak = nak; av = nav;
    }

    if (sp == 3) {   // tile 256: keys 4096..4111; only key 4096 (quad==0, reg 0) valid
        #pragma unroll
        for (int g = 0; g < 4; ++g) {
            f4 d = __builtin_amdgcn_mfma_f32_16x16x16f16(ak, qf[g], zero, 0, 0, 0);
            const float p0 = (quad == 0) ? EXP2F(d[0]) : 0.f;
            ls[g] += p0;
            const H4u pb = pack4u(p0, 0.f, 0.f, 0.f);
            acc[g] = __builtin_amdgcn_mfma_f32_16x16x16f16(av, pb.v, acc[g], 0, 0, 0);
        }
    }

    #pragma unroll
    for (int g = 0; g < 4; ++g) {
        float l = ls[g];
        l += __shfl_xor(l, 16);
        l += __shfl_xor(l, 32);
        const int qr = qbase + g*16 + l16;
        if (qr < NN) {
            const size_t row = (size_t)bidx*NN + qr;
            const float inv = 1.0f / l;   // per-split normalize: f16-safe range
            const H4u st = pack4u(acc[g][0]*inv, acc[g][1]*inv, acc[g][2]*inv, acc[g][3]*inv);
            *(h4*)(PACC + (row*NSP + sp)*DD + head*DH + quad*4) = st.v;
            if (quad == 0) PL[(row*HH + head)*NSP + sp] = l;
        }
    }
}

// ---------------- K3: merged-AO @ Wout + b via K=32 MFMA (R26: 8 waves) -------
// 513 blocks x 512 threads; block = 2 m-tiles. Merge phase: 512 threads over
// 32 tokens x 16 segs (dense 1KB PACC row blocks + float4 PL). Phase 2:
// wave w -> (tile w>>2, nt (w&3)*2); Wout loads inside kk-loop (TLP-hidden).
__global__ __launch_bounds__(512) void out_mfma(
    const _Float16* __restrict__ PACC,    // [ROWS][NSP][DD]
    const float* __restrict__ PL,         // [ROWS][HH][NSP]
    const _Float16* __restrict__ WoutT,   // [128][128]
    const float* __restrict__ bout,
    float* __restrict__ out)
{
    __shared__ _Float16 afl[32][136];     // [token(2 tiles)][dim], +8 pad
    const int tid  = threadIdx.x;
    const int wave = tid >> 6;            // 0..7
    const int lane = tid & 63;
    const int quad = lane >> 4, l16 = lane & 15;

    // ---- phase 1: merge splits for 32 tokens x 128 dims into LDS
    {
        const int t2  = tid >> 4;         // token 0..31 (across both tiles)
        const int seg = tid & 15;         // dim octet
        const int head = seg >> 1;
        const int arow = blockIdx.x*32 + t2;
        const int arc  = (arow < ROWS) ? arow : (ROWS - 1);
        const f4 lv = *(const f4*)(PL + ((size_t)arc*HH + head)*NSP);
        const float lsum = (lv[0] + lv[1]) + (lv[2] + lv[3]);
        const float inv = 1.0f / lsum;
        const _Float16* pb = PACC + (size_t)arc*NSP*DD + seg*8;
        float m[8] = {0,0,0,0,0,0,0,0};
        #pragma unroll
        for (int sp = 0; sp < NSP; ++sp) {
            const float s = lv[sp]*inv;
            const h8 p = *(const h8*)(pb + sp*DD);
            #pragma unroll
            for (int j = 0; j < 8; ++j) m[j] += s*(float)p[j];
        }
        H8u u;
#if __has_builtin(__builtin_amdgcn_cvt_pkrtz)
        u.p[0] = __builtin_amdgcn_cvt_pkrtz(m[0], m[1]);
        u.p[1] = __builtin_amdgcn_cvt_pkrtz(m[2], m[3]);
        u.p[2] = __builtin_amdgcn_cvt_pkrtz(m[4], m[5]);
        u.p[3] = __builtin_amdgcn_cvt_pkrtz(m[6], m[7]);
#else
        #pragma unroll
        for (int j = 0; j < 8; ++j) u.v[j] = (_Float16)m[j];
#endif
        *(h8*)&afl[t2][seg*8] = u.v;
    }
    __syncthreads();

    // ---- phase 2: GEMM vs WoutT; wave w -> tile (w>>2), n-tiles (w&3)*2, +1
    const int tw  = wave >> 2;
    const int nt  = (wave & 3)*2;
    const int wid = blockIdx.x*2 + tw;

    h8 af[4];
    #pragma unroll
    for (int kk = 0; kk < 4; ++kk)
        af[kk] = *(const h8*)&afl[tw*16 + l16][kk*32 + quad*8];

    const float b0 = bout[nt*16 + l16];
    const float b1 = bout[nt*16 + 16 + l16];
    f4 a0 = {b0,b0,b0,b0}, a1 = {b1,b1,b1,b1};
    #pragma unroll
    for (int kk = 0; kk < 4; ++kk) {
        const h8 wf0 = *(const h8*)(WoutT + (size_t)(nt*16      + l16)*DD + kk*32 + quad*8);
        const h8 wf1 = *(const h8*)(WoutT + (size_t)(nt*16 + 16 + l16)*DD + kk*32 + quad*8);
        a0 = __builtin_amdgcn_mfma_f32_16x16x32_f16(af[kk], wf0, a0, 0, 0, 0);
        a1 = __builtin_amdgcn_mfma_f32_16x16x32_f16(af[kk], wf1, a1, 0, 0, 0);
    }
    const int r0 = wid*16 + quad*4;
    #pragma unroll
    for (int r = 0; r < 4; ++r) {
        const int row = r0 + r;
        if (row < ROWS) {
            out[(size_t)row*DD + nt*16      + l16] = a0[r];
            out[(size_t)row*DD + nt*16 + 16 + l16] = a1[r];
        }
    }
}

extern "C" void kernel_launch(void* const* d_in, const int* in_sizes, int n_in,
                              void* d_out, int out_size, void* d_ws, size_t ws_size,
                              hipStream_t stream) {
    const float* x    = (const float*)d_in[0];
    const float* Wqkv = (const float*)d_in[1];
    const float* bqkv = (const float*)d_in[2];
    const float* Wout = (const float*)d_in[3];
    const float* bout = (const float*)d_in[4];
    for (int i = 0; i < n_in; ++i) {
        switch (in_sizes[i]) {
            case 2097664: x    = (const float*)d_in[i]; break;
            case 49152:   Wqkv = (const float*)d_in[i]; break;
            case 384:     bqkv = (const float*)d_in[i]; break;
            case 16384:   Wout = (const float*)d_in[i]; break;
            case 128:     bout = (const float*)d_in[i]; break;
            default: break;
        }
    }
    float* out = (float*)d_out;

    const size_t perh = (size_t)BH * NNP * DH;            // 2,105,344 f16
    _Float16* Qh   = (_Float16*)d_ws;                     // 4.21 MB
    _Float16* Kh   = Qh + perh;                           // 4.21 MB
    _Float16* Vt   = Kh + perh;                           // 4.21 MB
    _Float16* PACC = Vt + perh;                           // [ROWS][NSP][DD] f16 16.78 MB
    float*    PL    = (float*)(PACC + (size_t)NSP*ROWS*DD); // [ROWS][HH][NSP] 2.1 MB
    _Float16* WqkvT = (_Float16*)(PL + (size_t)NSP*ROWS*HH);// 96 KB
    _Float16* WoutT = WqkvT + 384*128;                    // 32 KB -> total ~31.6 MB

    const int prep_total = 384*128 + 128*128;

    hipLaunchKernelGGL(prep, dim3((prep_total + 255)/256), dim3(256), 0, stream,
                       Wqkv, Wout, WqkvT, WoutT);
    hipLaunchKernelGGL(qkv_mfma, dim3(MT), dim3(512), 0, stream,
                       x, WqkvT, bqkv, Qh, Kh, Vt);
    hipLaunchKernelGGL(attn_mfma, dim3(17, BH, NSP), dim3(256), 0, stream,
                       Qh, Kh, Vt, PACC, PL);
    hipLaunchKernelGGL(out_mfma, dim3((MT + 1)/2), dim3(512), 0, stream,
                       PACC, PL, WoutT, bout, out);
}